// Round 1
// baseline (3213.781 us; speedup 1.0000x reference)
//
#include <hip/hip_runtime.h>
#include <math.h>

#define C_DIM 1024
#define N_DIM 3072   // 3*C

// ---------------------------------------------------------------------------
// Kernel 1: qkv = x @ W + b      x:[T,1024]  W:[1024,3072]  b:[3072]
// 128x128 tile, BK=16, 256 threads, 8x8 per thread in 2x2 quadrants (4x4 each)
// ---------------------------------------------------------------------------
#define GT 128
#define GK 16

__device__ __forceinline__ void fma44(float (&c)[4][4], const float4& a, const float4& b) {
  const float av[4] = {a.x, a.y, a.z, a.w};
  const float bv[4] = {b.x, b.y, b.z, b.w};
#pragma unroll
  for (int i = 0; i < 4; ++i)
#pragma unroll
    for (int j = 0; j < 4; ++j) c[i][j] += av[i] * bv[j];
}

__global__ __launch_bounds__(256) void qkv_gemm(
    const float* __restrict__ x, const float* __restrict__ W,
    const float* __restrict__ bias, float* __restrict__ qkv, int T) {
  __shared__ float As[GK][GT];   // transposed A tile: As[k][m]
  __shared__ float Bs[GK][GT];   // Bs[k][n]
  const int tid  = threadIdx.x;
  const int row0 = blockIdx.y * GT;
  const int col0 = blockIdx.x * GT;
  const int tm = (tid >> 4) << 2;   // 0..60 step 4
  const int tn = (tid & 15) << 2;   // 0..60 step 4
  const int ar = tid >> 1;          // A-load row 0..127
  const int ac = (tid & 1) << 3;    // A-load k-offset 0/8
  const int br = tid >> 4;          // B-load k-row 0..15
  const int bc = (tid & 15) << 3;   // B-load col 0..120 step 8

  float acc[2][2][4][4] = {};

  const float* xp = x + (size_t)(row0 + ar) * C_DIM + ac;
  const float* wp = W + (size_t)br * N_DIM + col0 + bc;

  for (int k0 = 0; k0 < C_DIM; k0 += GK) {
    float4 a0 = *(const float4*)(xp + k0);
    float4 a1 = *(const float4*)(xp + k0 + 4);
    float4 b0 = *(const float4*)(wp + (size_t)k0 * N_DIM);
    float4 b1 = *(const float4*)(wp + (size_t)k0 * N_DIM + 4);
    __syncthreads();
    As[ac + 0][ar] = a0.x; As[ac + 1][ar] = a0.y;
    As[ac + 2][ar] = a0.z; As[ac + 3][ar] = a0.w;
    As[ac + 4][ar] = a1.x; As[ac + 5][ar] = a1.y;
    As[ac + 6][ar] = a1.z; As[ac + 7][ar] = a1.w;
    *(float4*)&Bs[br][bc]     = b0;
    *(float4*)&Bs[br][bc + 4] = b1;
    __syncthreads();
#pragma unroll
    for (int k = 0; k < GK; ++k) {
      float4 aL = *(const float4*)&As[k][tm];
      float4 aH = *(const float4*)&As[k][tm + 64];
      float4 bL = *(const float4*)&Bs[k][tn];
      float4 bH = *(const float4*)&Bs[k][tn + 64];
      fma44(acc[0][0], aL, bL);
      fma44(acc[0][1], aL, bH);
      fma44(acc[1][0], aH, bL);
      fma44(acc[1][1], aH, bH);
    }
  }

#pragma unroll
  for (int qi = 0; qi < 2; ++qi) {
#pragma unroll
    for (int i = 0; i < 4; ++i) {
      const int row = row0 + qi * 64 + tm + i;
#pragma unroll
      for (int qj = 0; qj < 2; ++qj) {
        const int col = col0 + qj * 64 + tn;
        float4 r;
        r.x = acc[qi][qj][i][0] + bias[col + 0];
        r.y = acc[qi][qj][i][1] + bias[col + 1];
        r.z = acc[qi][qj][i][2] + bias[col + 2];
        r.w = acc[qi][qj][i][3] + bias[col + 3];
        *(float4*)(qkv + (size_t)row * N_DIM + col) = r;
      }
    }
  }
}

// ---------------------------------------------------------------------------
// Kernel 2: flash-style causal attention, one wave (64 lanes) per query row.
// Each lane owns 16 of the 1024 components: float4 at offsets m*256 + lane*4.
// ---------------------------------------------------------------------------
__device__ __forceinline__ float dot4(const float4& a, const float4& b) {
  return a.x * b.x + a.y * b.y + a.z * b.z + a.w * b.w;
}

__global__ __launch_bounds__(256) void attn_flash(
    const float* __restrict__ qkv, const int* __restrict__ n_padd_p,
    float* __restrict__ out, int T) {
  const int lane = threadIdx.x & 63;
  const int wv   = threadIdx.x >> 6;
  const int idx  = blockIdx.x * 4 + wv;
  if (idx >= T) return;
  const int row = T - 1 - idx;          // longest rows scheduled first
  const int n_padd = *n_padd_p;
  const int co = lane << 2;

  const float* qr = qkv + (size_t)row * N_DIM;
  float4 q0 = *(const float4*)(qr + 0   + co);
  float4 q1 = *(const float4*)(qr + 256 + co);
  float4 q2 = *(const float4*)(qr + 512 + co);
  float4 q3 = *(const float4*)(qr + 768 + co);

  float4 y0 = {0.f, 0.f, 0.f, 0.f}, y1 = y0, y2 = y0, y3 = y0;
  float* op = out + (size_t)row * C_DIM;

  if (row < n_padd) {
    // reference: fully-masked row -> softmax of equal values -> uniform over ALL T keys
    for (int j = 0; j < T; ++j) {
      const float* vr = qkv + (size_t)j * N_DIM + 2 * C_DIM;
      float4 v0 = *(const float4*)(vr + 0   + co);
      float4 v1 = *(const float4*)(vr + 256 + co);
      float4 v2 = *(const float4*)(vr + 512 + co);
      float4 v3 = *(const float4*)(vr + 768 + co);
      y0.x += v0.x; y0.y += v0.y; y0.z += v0.z; y0.w += v0.w;
      y1.x += v1.x; y1.y += v1.y; y1.z += v1.z; y1.w += v1.w;
      y2.x += v2.x; y2.y += v2.y; y2.z += v2.z; y2.w += v2.w;
      y3.x += v3.x; y3.y += v3.y; y3.z += v3.z; y3.w += v3.w;
    }
    const float inv = 1.0f / (float)T;
    float4 r0 = {y0.x * inv, y0.y * inv, y0.z * inv, y0.w * inv};
    float4 r1 = {y1.x * inv, y1.y * inv, y1.z * inv, y1.w * inv};
    float4 r2 = {y2.x * inv, y2.y * inv, y2.z * inv, y2.w * inv};
    float4 r3 = {y3.x * inv, y3.y * inv, y3.z * inv, y3.w * inv};
    *(float4*)(op + 0   + co) = r0;
    *(float4*)(op + 256 + co) = r1;
    *(float4*)(op + 512 + co) = r2;
    *(float4*)(op + 768 + co) = r3;
    return;
  }

  float mrun = -3.0e38f;
  float lrun = 0.0f;
  const float scale = 0.03125f;   // 1/sqrt(1024)

  for (int j = n_padd; j <= row; ++j) {
    const float* kr = qkv + (size_t)j * N_DIM + C_DIM;
    float4 k0 = *(const float4*)(kr + 0   + co);
    float4 k1 = *(const float4*)(kr + 256 + co);
    float4 k2 = *(const float4*)(kr + 512 + co);
    float4 k3 = *(const float4*)(kr + 768 + co);
    float s = dot4(q0, k0) + dot4(q1, k1) + dot4(q2, k2) + dot4(q3, k3);
    // 64-lane butterfly: every lane ends with the identical full sum
    s += __shfl_xor(s, 32);
    s += __shfl_xor(s, 16);
    s += __shfl_xor(s, 8);
    s += __shfl_xor(s, 4);
    s += __shfl_xor(s, 2);
    s += __shfl_xor(s, 1);
    s *= scale;

    const float* vr = qkv + (size_t)j * N_DIM + 2 * C_DIM;
    float4 v0 = *(const float4*)(vr + 0   + co);
    float4 v1 = *(const float4*)(vr + 256 + co);
    float4 v2 = *(const float4*)(vr + 512 + co);
    float4 v3 = *(const float4*)(vr + 768 + co);

    if (s <= mrun) {            // wave-uniform branch (s identical on all lanes)
      const float p = __expf(s - mrun);
      lrun += p;
      y0.x += p * v0.x; y0.y += p * v0.y; y0.z += p * v0.z; y0.w += p * v0.w;
      y1.x += p * v1.x; y1.y += p * v1.y; y1.z += p * v1.z; y1.w += p * v1.w;
      y2.x += p * v2.x; y2.y += p * v2.y; y2.z += p * v2.z; y2.w += p * v2.w;
      y3.x += p * v3.x; y3.y += p * v3.y; y3.z += p * v3.z; y3.w += p * v3.w;
    } else {                    // new max: rescale (rare, ~ln(T) times per row)
      const float cf = __expf(mrun - s);
      mrun = s;
      lrun = lrun * cf + 1.0f;
      y0.x = y0.x * cf + v0.x; y0.y = y0.y * cf + v0.y;
      y0.z = y0.z * cf + v0.z; y0.w = y0.w * cf + v0.w;
      y1.x = y1.x * cf + v1.x; y1.y = y1.y * cf + v1.y;
      y1.z = y1.z * cf + v1.z; y1.w = y1.w * cf + v1.w;
      y2.x = y2.x * cf + v2.x; y2.y = y2.y * cf + v2.y;
      y2.z = y2.z * cf + v2.z; y2.w = y2.w * cf + v2.w;
      y3.x = y3.x * cf + v3.x; y3.y = y3.y * cf + v3.y;
      y3.z = y3.z * cf + v3.z; y3.w = y3.w * cf + v3.w;
    }
  }

  const float inv = 1.0f / lrun;
  float4 r0 = {y0.x * inv, y0.y * inv, y0.z * inv, y0.w * inv};
  float4 r1 = {y1.x * inv, y1.y * inv, y1.z * inv, y1.w * inv};
  float4 r2 = {y2.x * inv, y2.y * inv, y2.z * inv, y2.w * inv};
  float4 r3 = {y3.x * inv, y3.y * inv, y3.z * inv, y3.w * inv};
  *(float4*)(op + 0   + co) = r0;
  *(float4*)(op + 256 + co) = r1;
  *(float4*)(op + 512 + co) = r2;
  *(float4*)(op + 768 + co) = r3;
}

// ---------------------------------------------------------------------------
extern "C" void kernel_launch(void* const* d_in, const int* in_sizes, int n_in,
                              void* d_out, int out_size, void* d_ws, size_t ws_size,
                              hipStream_t stream) {
  const float* x    = (const float*)d_in[0];
  const float* W    = (const float*)d_in[1];
  const float* b    = (const float*)d_in[2];
  const int* n_padd = (const int*)d_in[3];
  float* out = (float*)d_out;
  float* qkv = (float*)d_ws;              // [T, 3072] fp32 = 48 MB at T=4096

  const int T = in_sizes[0] / C_DIM;

  dim3 g1(N_DIM / GT, (T + GT - 1) / GT);
  qkv_gemm<<<g1, 256, 0, stream>>>(x, W, b, qkv, T);

  const int nblk = (T + 3) / 4;           // 4 waves/block, 1 row/wave
  attn_flash<<<nblk, 256, 0, stream>>>(qkv, n_padd, out, T);
}

// Round 2
// 2889.309 us; speedup vs baseline: 1.1123x; 1.1123x over previous
//
#include <hip/hip_runtime.h>
#include <math.h>

#define C_DIM 1024
#define N_DIM 3072   // 3*C

// ---------------------------------------------------------------------------
// Kernel 1: qkv = x @ W + b      (unchanged from R1 baseline)
// ---------------------------------------------------------------------------
#define GT 128
#define GK 16

__device__ __forceinline__ void fma44(float (&c)[4][4], const float4& a, const float4& b) {
  const float av[4] = {a.x, a.y, a.z, a.w};
  const float bv[4] = {b.x, b.y, b.z, b.w};
#pragma unroll
  for (int i = 0; i < 4; ++i)
#pragma unroll
    for (int j = 0; j < 4; ++j) c[i][j] += av[i] * bv[j];
}

__global__ __launch_bounds__(256) void qkv_gemm(
    const float* __restrict__ x, const float* __restrict__ W,
    const float* __restrict__ bias, float* __restrict__ qkv, int T) {
  __shared__ float As[GK][GT];
  __shared__ float Bs[GK][GT];
  const int tid  = threadIdx.x;
  const int row0 = blockIdx.y * GT;
  const int col0 = blockIdx.x * GT;
  const int tm = (tid >> 4) << 2;
  const int tn = (tid & 15) << 2;
  const int ar = tid >> 1;
  const int ac = (tid & 1) << 3;
  const int br = tid >> 4;
  const int bc = (tid & 15) << 3;

  float acc[2][2][4][4] = {};

  const float* xp = x + (size_t)(row0 + ar) * C_DIM + ac;
  const float* wp = W + (size_t)br * N_DIM + col0 + bc;

  for (int k0 = 0; k0 < C_DIM; k0 += GK) {
    float4 a0 = *(const float4*)(xp + k0);
    float4 a1 = *(const float4*)(xp + k0 + 4);
    float4 b0 = *(const float4*)(wp + (size_t)k0 * N_DIM);
    float4 b1 = *(const float4*)(wp + (size_t)k0 * N_DIM + 4);
    __syncthreads();
    As[ac + 0][ar] = a0.x; As[ac + 1][ar] = a0.y;
    As[ac + 2][ar] = a0.z; As[ac + 3][ar] = a0.w;
    As[ac + 4][ar] = a1.x; As[ac + 5][ar] = a1.y;
    As[ac + 6][ar] = a1.z; As[ac + 7][ar] = a1.w;
    *(float4*)&Bs[br][bc]     = b0;
    *(float4*)&Bs[br][bc + 4] = b1;
    __syncthreads();
#pragma unroll
    for (int k = 0; k < GK; ++k) {
      float4 aL = *(const float4*)&As[k][tm];
      float4 aH = *(const float4*)&As[k][tm + 64];
      float4 bL = *(const float4*)&Bs[k][tn];
      float4 bH = *(const float4*)&Bs[k][tn + 64];
      fma44(acc[0][0], aL, bL);
      fma44(acc[0][1], aL, bH);
      fma44(acc[1][0], aH, bL);
      fma44(acc[1][1], aH, bH);
    }
  }

#pragma unroll
  for (int qi = 0; qi < 2; ++qi) {
#pragma unroll
    for (int i = 0; i < 4; ++i) {
      const int row = row0 + qi * 64 + tm + i;
#pragma unroll
      for (int qj = 0; qj < 2; ++qj) {
        const int col = col0 + qj * 64 + tn;
        float4 r;
        r.x = acc[qi][qj][i][0] + bias[col + 0];
        r.y = acc[qi][qj][i][1] + bias[col + 1];
        r.z = acc[qi][qj][i][2] + bias[col + 2];
        r.w = acc[qi][qj][i][3] + bias[col + 3];
        *(float4*)(qkv + (size_t)row * N_DIM + col) = r;
      }
    }
  }
}

// ---------------------------------------------------------------------------
// Kernel 2: tiled flash attention (fp32, compute-bound form)
// Block = 256 threads. BQ=16 query rows per block, key chunks of BKEY=256.
// Score phase: 16x256 GEMM, 4x4 register fragments (wave w owns rows 4w..4w+3).
// PV phase: each thread owns a 4-col strip of O for all 16 rows.
// ---------------------------------------------------------------------------
#define BQ   16
#define BKEY 256
#define KC   16

__device__ __forceinline__ void fmarow(float (&s)[4][4], float a0, float a1,
                                       float a2, float a3, const float4& b) {
  s[0][0] += a0 * b.x; s[0][1] += a0 * b.y; s[0][2] += a0 * b.z; s[0][3] += a0 * b.w;
  s[1][0] += a1 * b.x; s[1][1] += a1 * b.y; s[1][2] += a1 * b.z; s[1][3] += a1 * b.w;
  s[2][0] += a2 * b.x; s[2][1] += a2 * b.y; s[2][2] += a2 * b.z; s[2][3] += a2 * b.w;
  s[3][0] += a3 * b.x; s[3][1] += a3 * b.y; s[3][2] += a3 * b.z; s[3][3] += a3 * b.w;
}

__global__ __launch_bounds__(256) void attn_tiled(
    const float* __restrict__ qkv, const int* __restrict__ n_padd_p,
    float* __restrict__ out, int T) {
  __shared__ float Qs[BQ][KC];          // 1 KB
  __shared__ float Ks[KC][BKEY];        // 16 KB, transposed: Ks[k][j]
  __shared__ float Ps[BQ][BKEY];        // 16 KB
  __shared__ float alpha_s[BQ];
  __shared__ float l_s[BQ];

  const int tid = threadIdx.x;
  const int ntiles = T / BQ;
  const int tile = ntiles - 1 - blockIdx.x;   // longest tiles first
  const int row0 = tile * BQ;
  const int rg = tid >> 6;                     // wave id = row-group (rows 4rg..4rg+3)
  const int cg = tid & 63;                     // col-group (cols 4cg..4cg+3)
  const int c4 = tid << 2;                     // output col strip
  const int np = *n_padd_p;
  const float scale = 0.03125f;                // 1/sqrt(1024)

  float4 o[BQ];
#pragma unroll
  for (int r = 0; r < BQ; ++r) o[r] = make_float4(0.f, 0.f, 0.f, 0.f);
  float m_i[4], l_i[4];
#pragma unroll
  for (int i = 0; i < 4; ++i) { m_i[i] = -3.0e38f; l_i[i] = 0.0f; }

  const int kmax = row0 + BQ;                  // keys needed: [0, kmax)
  const int nchunks = (kmax + BKEY - 1) / BKEY;

  const int qrow = tid >> 2;                   // for Q staging (tid<64)
  const int qk4  = (tid & 3) << 2;

  for (int ch = 0; ch < nchunks; ++ch) {
    const int kc0 = ch * BKEY;
    float s[4][4] = {};

    const float* kbase = qkv + (size_t)(kc0 + tid) * N_DIM + C_DIM;
    const float* qbase = qkv + (size_t)(row0 + qrow) * N_DIM + qk4;

    for (int k0 = 0; k0 < C_DIM; k0 += KC) {
      float4 ka = *(const float4*)(kbase + k0);
      float4 kb = *(const float4*)(kbase + k0 + 4);
      float4 kc_ = *(const float4*)(kbase + k0 + 8);
      float4 kd = *(const float4*)(kbase + k0 + 12);
      float4 qv;
      if (tid < 64) qv = *(const float4*)(qbase + k0);
      __syncthreads();   // previous iter's LDS reads (and prev chunk's Ps reads) done
      Ks[ 0][tid] = ka.x; Ks[ 1][tid] = ka.y; Ks[ 2][tid] = ka.z; Ks[ 3][tid] = ka.w;
      Ks[ 4][tid] = kb.x; Ks[ 5][tid] = kb.y; Ks[ 6][tid] = kb.z; Ks[ 7][tid] = kb.w;
      Ks[ 8][tid] = kc_.x; Ks[ 9][tid] = kc_.y; Ks[10][tid] = kc_.z; Ks[11][tid] = kc_.w;
      Ks[12][tid] = kd.x; Ks[13][tid] = kd.y; Ks[14][tid] = kd.z; Ks[15][tid] = kd.w;
      if (tid < 64) *(float4*)&Qs[qrow][qk4] = qv;
      __syncthreads();
#pragma unroll
      for (int kk = 0; kk < KC; kk += 4) {
        float4 q0 = *(const float4*)&Qs[rg * 4 + 0][kk];
        float4 q1 = *(const float4*)&Qs[rg * 4 + 1][kk];
        float4 q2 = *(const float4*)&Qs[rg * 4 + 2][kk];
        float4 q3 = *(const float4*)&Qs[rg * 4 + 3][kk];
        float4 k0f = *(const float4*)&Ks[kk + 0][cg << 2];
        float4 k1f = *(const float4*)&Ks[kk + 1][cg << 2];
        float4 k2f = *(const float4*)&Ks[kk + 2][cg << 2];
        float4 k3f = *(const float4*)&Ks[kk + 3][cg << 2];
        fmarow(s, q0.x, q1.x, q2.x, q3.x, k0f);
        fmarow(s, q0.y, q1.y, q2.y, q3.y, k1f);
        fmarow(s, q0.z, q1.z, q2.z, q3.z, k2f);
        fmarow(s, q0.w, q1.w, q2.w, q3.w, k3f);
      }
    }

    // ---- online softmax (per wave: 4 rows, reduce over 64 lanes = 256 cols)
    float alpha[4];
#pragma unroll
    for (int i = 0; i < 4; ++i) {
      const int rowg = row0 + rg * 4 + i;
      float sv[4];
      float mx = -3.0e38f;
#pragma unroll
      for (int j = 0; j < 4; ++j) {
        const int jg = kc0 + (cg << 2) + j;
        const bool valid = (jg <= rowg) && (jg >= np);
        sv[j] = valid ? s[i][j] * scale : -3.0e38f;
        mx = fmaxf(mx, sv[j]);
      }
      mx = fmaxf(mx, __shfl_xor(mx, 32));
      mx = fmaxf(mx, __shfl_xor(mx, 16));
      mx = fmaxf(mx, __shfl_xor(mx, 8));
      mx = fmaxf(mx, __shfl_xor(mx, 4));
      mx = fmaxf(mx, __shfl_xor(mx, 2));
      mx = fmaxf(mx, __shfl_xor(mx, 1));
      const float m_new = fmaxf(m_i[i], mx);
      alpha[i] = __expf(m_i[i] - m_new);
      m_i[i] = m_new;
      float ls = 0.f;
#pragma unroll
      for (int j = 0; j < 4; ++j) {
        const float p = __expf(sv[j] - m_new);
        sv[j] = p;
        ls += p;
      }
      ls += __shfl_xor(ls, 32);
      ls += __shfl_xor(ls, 16);
      ls += __shfl_xor(ls, 8);
      ls += __shfl_xor(ls, 4);
      ls += __shfl_xor(ls, 2);
      ls += __shfl_xor(ls, 1);
      l_i[i] = l_i[i] * alpha[i] + ls;
      *(float4*)&Ps[rg * 4 + i][cg << 2] = make_float4(sv[0], sv[1], sv[2], sv[3]);
    }
    if (cg == 0) {
#pragma unroll
      for (int i = 0; i < 4; ++i) alpha_s[rg * 4 + i] = alpha[i];
    }
    __syncthreads();

    // ---- rescale O, then O += P @ V
#pragma unroll
    for (int r = 0; r < BQ; ++r) {
      const float a = alpha_s[r];
      o[r].x *= a; o[r].y *= a; o[r].z *= a; o[r].w *= a;
    }
    const int jend = min(BKEY, kmax - kc0);
    const float* vbase = qkv + (size_t)kc0 * N_DIM + 2 * C_DIM + c4;
    for (int j4 = 0; j4 < jend; j4 += 4) {
      float4 v0 = *(const float4*)(vbase + (size_t)(j4 + 0) * N_DIM);
      float4 v1 = *(const float4*)(vbase + (size_t)(j4 + 1) * N_DIM);
      float4 v2 = *(const float4*)(vbase + (size_t)(j4 + 2) * N_DIM);
      float4 v3 = *(const float4*)(vbase + (size_t)(j4 + 3) * N_DIM);
#pragma unroll
      for (int r = 0; r < BQ; ++r) {
        float4 p = *(const float4*)&Ps[r][j4];
        o[r].x += p.x * v0.x + p.y * v1.x + p.z * v2.x + p.w * v3.x;
        o[r].y += p.x * v0.y + p.y * v1.y + p.z * v2.y + p.w * v3.y;
        o[r].z += p.x * v0.z + p.y * v1.z + p.z * v2.z + p.w * v3.z;
        o[r].w += p.x * v0.w + p.y * v1.w + p.z * v2.w + p.w * v3.w;
      }
    }
    // next chunk's first __syncthreads guards Ps/Ks reuse
  }

  // ---- epilogue: normalize and store
  if (cg == 0) {
#pragma unroll
    for (int i = 0; i < 4; ++i) l_s[rg * 4 + i] = l_i[i];
  }
  __syncthreads();
#pragma unroll
  for (int r = 0; r < BQ; ++r) {
    const float inv = 1.0f / l_s[r];
    float4 y = o[r];
    y.x *= inv; y.y *= inv; y.z *= inv; y.w *= inv;
    *(float4*)(out + (size_t)(row0 + r) * C_DIM + c4) = y;
  }

  // ---- padded query rows (< n_padd): uniform attention over ALL T keys
  int pc = np - row0;
  if (pc > 0) {
    pc = min(pc, BQ);
    float4 acc = make_float4(0.f, 0.f, 0.f, 0.f);
    const float* vb = qkv + 2 * C_DIM + c4;
    for (int j = 0; j < T; ++j) {
      float4 v = *(const float4*)(vb + (size_t)j * N_DIM);
      acc.x += v.x; acc.y += v.y; acc.z += v.z; acc.w += v.w;
    }
    const float inv = 1.0f / (float)T;
    acc.x *= inv; acc.y *= inv; acc.z *= inv; acc.w *= inv;
    for (int r = 0; r < pc; ++r)
      *(float4*)(out + (size_t)(row0 + r) * C_DIM + c4) = acc;
  }
}

// ---------------------------------------------------------------------------
extern "C" void kernel_launch(void* const* d_in, const int* in_sizes, int n_in,
                              void* d_out, int out_size, void* d_ws, size_t ws_size,
                              hipStream_t stream) {
  const float* x    = (const float*)d_in[0];
  const float* W    = (const float*)d_in[1];
  const float* b    = (const float*)d_in[2];
  const int* n_padd = (const int*)d_in[3];
  float* out = (float*)d_out;
  float* qkv = (float*)d_ws;              // [T, 3072] fp32 = 48 MB at T=4096

  const int T = in_sizes[0] / C_DIM;

  dim3 g1(N_DIM / GT, (T + GT - 1) / GT);
  qkv_gemm<<<g1, 256, 0, stream>>>(x, W, b, qkv, T);

  const int ntiles = T / BQ;
  attn_tiled<<<ntiles, 256, 0, stream>>>(qkv, n_padd, out, T);
}

// Round 4
// 1692.008 us; speedup vs baseline: 1.8994x; 1.7076x over previous
//
#include <hip/hip_runtime.h>
#include <math.h>

#define C_DIM 1024
#define N_DIM 3072   // 3*C

// ---------------------------------------------------------------------------
// Kernel 1: qkv = x @ W + b      (unchanged — ~95 TF, 60% of fp32 peak)
// ---------------------------------------------------------------------------
#define GT 128
#define GK 16

__device__ __forceinline__ void fma44(float (&c)[4][4], const float4& a, const float4& b) {
  const float av[4] = {a.x, a.y, a.z, a.w};
  const float bv[4] = {b.x, b.y, b.z, b.w};
#pragma unroll
  for (int i = 0; i < 4; ++i)
#pragma unroll
    for (int j = 0; j < 4; ++j) c[i][j] += av[i] * bv[j];
}

__global__ __launch_bounds__(256) void qkv_gemm(
    const float* __restrict__ x, const float* __restrict__ W,
    const float* __restrict__ bias, float* __restrict__ qkv, int T) {
  __shared__ float As[GK][GT];
  __shared__ float Bs[GK][GT];
  const int tid  = threadIdx.x;
  const int row0 = blockIdx.y * GT;
  const int col0 = blockIdx.x * GT;
  const int tm = (tid >> 4) << 2;
  const int tn = (tid & 15) << 2;
  const int ar = tid >> 1;
  const int ac = (tid & 1) << 3;
  const int br = tid >> 4;
  const int bc = (tid & 15) << 3;

  float acc[2][2][4][4] = {};

  const float* xp = x + (size_t)(row0 + ar) * C_DIM + ac;
  const float* wp = W + (size_t)br * N_DIM + col0 + bc;

  for (int k0 = 0; k0 < C_DIM; k0 += GK) {
    float4 a0 = *(const float4*)(xp + k0);
    float4 a1 = *(const float4*)(xp + k0 + 4);
    float4 b0 = *(const float4*)(wp + (size_t)k0 * N_DIM);
    float4 b1 = *(const float4*)(wp + (size_t)k0 * N_DIM + 4);
    __syncthreads();
    As[ac + 0][ar] = a0.x; As[ac + 1][ar] = a0.y;
    As[ac + 2][ar] = a0.z; As[ac + 3][ar] = a0.w;
    As[ac + 4][ar] = a1.x; As[ac + 5][ar] = a1.y;
    As[ac + 6][ar] = a1.z; As[ac + 7][ar] = a1.w;
    *(float4*)&Bs[br][bc]     = b0;
    *(float4*)&Bs[br][bc + 4] = b1;
    __syncthreads();
#pragma unroll
    for (int k = 0; k < GK; ++k) {
      float4 aL = *(const float4*)&As[k][tm];
      float4 aH = *(const float4*)&As[k][tm + 64];
      float4 bL = *(const float4*)&Bs[k][tn];
      float4 bH = *(const float4*)&Bs[k][tn + 64];
      fma44(acc[0][0], aL, bL);
      fma44(acc[0][1], aL, bH);
      fma44(acc[1][0], aH, bL);
      fma44(acc[1][1], aH, bH);
    }
  }

#pragma unroll
  for (int qi = 0; qi < 2; ++qi) {
#pragma unroll
    for (int i = 0; i < 4; ++i) {
      const int row = row0 + qi * 64 + tm + i;
#pragma unroll
      for (int qj = 0; qj < 2; ++qj) {
        const int col = col0 + qj * 64 + tn;
        float4 r;
        r.x = acc[qi][qj][i][0] + bias[col + 0];
        r.y = acc[qi][qj][i][1] + bias[col + 1];
        r.z = acc[qi][qj][i][2] + bias[col + 2];
        r.w = acc[qi][qj][i][3] + bias[col + 3];
        *(float4*)(qkv + (size_t)row * N_DIM + col) = r;
      }
    }
  }
}

// ---------------------------------------------------------------------------
// Kernel 2: flash attention, split-K halves. Block = (tile of 16 rows, half).
// Wave lane layout: rg = lane>>4 (4 row-groups x 4 rows), cgl = lane&15 col
// sub-lane -> K LDS reads are 4-way shared (256B/instr, 2-way banks = free).
// Output is UNNORMALIZED O plus (m,l) per row-half; merged by kernel 3.
// ---------------------------------------------------------------------------
#define BQ   16
#define BKEY 256
#define KC   16

__device__ __forceinline__ void fmarow(float (&s)[4][4], float a0, float a1,
                                       float a2, float a3, const float4& b) {
  s[0][0] += a0 * b.x; s[0][1] += a0 * b.y; s[0][2] += a0 * b.z; s[0][3] += a0 * b.w;
  s[1][0] += a1 * b.x; s[1][1] += a1 * b.y; s[1][2] += a1 * b.z; s[1][3] += a1 * b.w;
  s[2][0] += a2 * b.x; s[2][1] += a2 * b.y; s[2][2] += a2 * b.z; s[2][3] += a2 * b.w;
  s[3][0] += a3 * b.x; s[3][1] += a3 * b.y; s[3][2] += a3 * b.z; s[3][3] += a3 * b.w;
}

__global__ __launch_bounds__(256) void attn_flash2(
    const float* __restrict__ qkv, const int* __restrict__ n_padd_p,
    float* __restrict__ out, float* __restrict__ part1,
    float2* __restrict__ ml, int T) {
  __shared__ float Qs[BQ][20];          // k-window of Q, padded stride
  __shared__ float Ks[KC][BKEY];        // transposed K tile
  __shared__ float Ps[BQ][BKEY];        // probabilities
  __shared__ float mw[4][BQ];           // per-wave partial max
  __shared__ float lw[4][BQ];           // per-wave partial sum
  __shared__ float alpha_s[BQ];

  const int tid  = threadIdx.x;
  const int lane = tid & 63;
  const int w    = tid >> 6;
  const int rg   = lane >> 4;           // row sub-group: rows rg*4..rg*4+3
  const int cgl  = lane & 15;           // col sub-lane within wave
  const int cg   = (w << 4) | cgl;      // col group 0..63 -> cols cg*4..cg*4+3
  const int r0   = rg << 2;
  const int c4   = tid << 2;            // O column strip

  const int ntiles = T / BQ;
  const int tile = ntiles - 1 - (blockIdx.x >> 1);  // longest tiles first
  const int half = blockIdx.x & 1;
  const int row0 = tile * BQ;
  const int np   = *n_padd_p;
  const float scale = 0.03125f;         // 1/sqrt(1024)

  const int kmax = row0 + BQ;
  const int nch_total = (kmax + BKEY - 1) / BKEY;
  const int nch0  = nch_total >> 1;
  const int ch_lo = half ? nch0 : 0;
  const int ch_hi = half ? nch_total : nch0;

  float4 o[BQ];
#pragma unroll
  for (int r = 0; r < BQ; ++r) o[r] = make_float4(0.f, 0.f, 0.f, 0.f);
  float m_i[4], l_i[4];
#pragma unroll
  for (int i = 0; i < 4; ++i) { m_i[i] = -3.0e38f; l_i[i] = 0.0f; }

  const int qrow = tid >> 2;            // Q staging (tid < 64)
  const int qk4  = (tid & 3) << 2;

  for (int ch = ch_lo; ch < ch_hi; ++ch) {
    const int kc0 = ch * BKEY;
    float s[4][4] = {};

    int krow = kc0 + tid; if (krow >= T) krow = T - 1;   // clamp (masked anyway)
    const float* kbase = qkv + (size_t)krow * N_DIM + C_DIM;
    const float* qbase = qkv + (size_t)(row0 + qrow) * N_DIM + qk4;

    for (int k0 = 0; k0 < C_DIM; k0 += KC) {
      float4 ka = *(const float4*)(kbase + k0);
      float4 kb = *(const float4*)(kbase + k0 + 4);
      float4 kc_ = *(const float4*)(kbase + k0 + 8);
      float4 kd = *(const float4*)(kbase + k0 + 12);
      float4 qv;
      if (tid < 64) qv = *(const float4*)(qbase + k0);
      __syncthreads();
      Ks[ 0][tid] = ka.x; Ks[ 1][tid] = ka.y; Ks[ 2][tid] = ka.z; Ks[ 3][tid] = ka.w;
      Ks[ 4][tid] = kb.x; Ks[ 5][tid] = kb.y; Ks[ 6][tid] = kb.z; Ks[ 7][tid] = kb.w;
      Ks[ 8][tid] = kc_.x; Ks[ 9][tid] = kc_.y; Ks[10][tid] = kc_.z; Ks[11][tid] = kc_.w;
      Ks[12][tid] = kd.x; Ks[13][tid] = kd.y; Ks[14][tid] = kd.z; Ks[15][tid] = kd.w;
      if (tid < 64) *(float4*)&Qs[qrow][qk4] = qv;
      __syncthreads();
#pragma unroll
      for (int kk = 0; kk < KC; kk += 4) {
        float4 q0 = *(const float4*)&Qs[r0 + 0][kk];
        float4 q1 = *(const float4*)&Qs[r0 + 1][kk];
        float4 q2 = *(const float4*)&Qs[r0 + 2][kk];
        float4 q3 = *(const float4*)&Qs[r0 + 3][kk];
        float4 k0f = *(const float4*)&Ks[kk + 0][cg << 2];
        float4 k1f = *(const float4*)&Ks[kk + 1][cg << 2];
        float4 k2f = *(const float4*)&Ks[kk + 2][cg << 2];
        float4 k3f = *(const float4*)&Ks[kk + 3][cg << 2];
        fmarow(s, q0.x, q1.x, q2.x, q3.x, k0f);
        fmarow(s, q0.y, q1.y, q2.y, q3.y, k1f);
        fmarow(s, q0.z, q1.z, q2.z, q3.z, k2f);
        fmarow(s, q0.w, q1.w, q2.w, q3.w, k3f);
      }
    }

    // ---- online softmax: 16-lane subgroup reduce + cross-wave LDS combine
#pragma unroll
    for (int i = 0; i < 4; ++i) {
      const int rowg = row0 + r0 + i;
      float mx = -3.0e38f;
#pragma unroll
      for (int j = 0; j < 4; ++j) {
        const int jg = kc0 + (cg << 2) + j;
        const bool valid = (jg <= rowg) && (jg >= np);
        s[i][j] = valid ? s[i][j] * scale : -3.0e38f;
        mx = fmaxf(mx, s[i][j]);
      }
      mx = fmaxf(mx, __shfl_xor(mx, 1));
      mx = fmaxf(mx, __shfl_xor(mx, 2));
      mx = fmaxf(mx, __shfl_xor(mx, 4));
      mx = fmaxf(mx, __shfl_xor(mx, 8));
      if (cgl == 0) mw[w][r0 + i] = mx;
    }
    __syncthreads();
    float alpha[4];
#pragma unroll
    for (int i = 0; i < 4; ++i) {
      const float mxb = fmaxf(fmaxf(mw[0][r0 + i], mw[1][r0 + i]),
                              fmaxf(mw[2][r0 + i], mw[3][r0 + i]));
      const float m_new = fmaxf(m_i[i], mxb);
      alpha[i] = __expf(m_i[i] - m_new);
      m_i[i] = m_new;
      float4 p;
      p.x = (s[i][0] > -1.0e30f) ? __expf(s[i][0] - m_new) : 0.0f;
      p.y = (s[i][1] > -1.0e30f) ? __expf(s[i][1] - m_new) : 0.0f;
      p.z = (s[i][2] > -1.0e30f) ? __expf(s[i][2] - m_new) : 0.0f;
      p.w = (s[i][3] > -1.0e30f) ? __expf(s[i][3] - m_new) : 0.0f;
      float ls = p.x + p.y + p.z + p.w;
      ls += __shfl_xor(ls, 1);
      ls += __shfl_xor(ls, 2);
      ls += __shfl_xor(ls, 4);
      ls += __shfl_xor(ls, 8);
      if (cgl == 0) lw[w][r0 + i] = ls;
      *(float4*)&Ps[r0 + i][cg << 2] = p;
      // FIX (R3 bug): broadcast alpha via wave-0's subgroup leaders
      // (tid 0,16,32,48). Old condition `tid == (r0<<4)` only ever matched
      // tid==0, leaving alpha_s[4..15] as 0xAA poison -> NaN.
      if (w == 0 && cgl == 0) alpha_s[r0 + i] = alpha[i];
    }
    __syncthreads();
#pragma unroll
    for (int i = 0; i < 4; ++i)
      l_i[i] = l_i[i] * alpha[i] +
               (lw[0][r0 + i] + lw[1][r0 + i] + lw[2][r0 + i] + lw[3][r0 + i]);

    // ---- rescale O, then O += P @ V
#pragma unroll
    for (int r = 0; r < BQ; ++r) {
      const float a = alpha_s[r];
      o[r].x *= a; o[r].y *= a; o[r].z *= a; o[r].w *= a;
    }
    const int jend = min(BKEY, kmax - kc0);
    const float* vbase = qkv + (size_t)kc0 * N_DIM + 2 * C_DIM + c4;
    for (int j4 = 0; j4 < jend; j4 += 4) {
      float4 v0 = *(const float4*)(vbase + (size_t)(j4 + 0) * N_DIM);
      float4 v1 = *(const float4*)(vbase + (size_t)(j4 + 1) * N_DIM);
      float4 v2 = *(const float4*)(vbase + (size_t)(j4 + 2) * N_DIM);
      float4 v3 = *(const float4*)(vbase + (size_t)(j4 + 3) * N_DIM);
#pragma unroll
      for (int r = 0; r < BQ; ++r) {
        float4 p = *(const float4*)&Ps[r][j4];
        o[r].x += p.x * v0.x + p.y * v1.x + p.z * v2.x + p.w * v3.x;
        o[r].y += p.x * v0.y + p.y * v1.y + p.z * v2.y + p.w * v3.y;
        o[r].z += p.x * v0.z + p.y * v1.z + p.z * v2.z + p.w * v3.z;
        o[r].w += p.x * v0.w + p.y * v1.w + p.z * v2.w + p.w * v3.w;
      }
    }
  }

  // ---- epilogue: store unnormalized O + (m,l)
  float* dst = half ? part1 : out;
#pragma unroll
  for (int r = 0; r < BQ; ++r)
    *(float4*)(dst + (size_t)(row0 + r) * C_DIM + c4) = o[r];
  if (w == 0 && cgl == 0) {
#pragma unroll
    for (int i = 0; i < 4; ++i)
      ml[(size_t)(row0 + r0 + i) * 2 + half] = make_float2(m_i[i], l_i[i]);
  }

  // ---- padded rows (< n_padd): uniform over ALL T keys, final value (h0 only)
  if (half == 0 && np > row0) {
    const int pc = min(np - row0, BQ);
    float4 acc = make_float4(0.f, 0.f, 0.f, 0.f);
    const float* vb = qkv + 2 * C_DIM + c4;
    for (int j = 0; j < T; ++j) {
      float4 v = *(const float4*)(vb + (size_t)j * N_DIM);
      acc.x += v.x; acc.y += v.y; acc.z += v.z; acc.w += v.w;
    }
    const float inv = 1.0f / (float)T;
    acc.x *= inv; acc.y *= inv; acc.z *= inv; acc.w *= inv;
    for (int r = 0; r < pc; ++r)
      *(float4*)(out + (size_t)(row0 + r) * C_DIM + c4) = acc;
  }
}

// ---------------------------------------------------------------------------
// Kernel 3: merge the two halves.  out = (w0*O0 + w1*O1) / (w0*l0 + w1*l1)
// ---------------------------------------------------------------------------
__global__ __launch_bounds__(256) void attn_merge(
    float* __restrict__ out, const float* __restrict__ part1,
    const float2* __restrict__ ml, const int* __restrict__ n_padd_p, int T) {
  const int row = blockIdx.x;
  if (row < *n_padd_p) return;   // final value already written by h0 block
  const float2 a = ml[(size_t)row * 2 + 0];
  const float2 b = ml[(size_t)row * 2 + 1];
  const float m  = fmaxf(a.x, b.x);
  const float w0 = __expf(a.x - m);
  const float w1 = __expf(b.x - m);
  const float inv = 1.0f / (w0 * a.y + w1 * b.y);
  const int c = threadIdx.x << 2;
  float4 o0 = *(const float4*)(out   + (size_t)row * C_DIM + c);
  float4 o1 = *(const float4*)(part1 + (size_t)row * C_DIM + c);
  float4 r;
  r.x = (w0 * o0.x + w1 * o1.x) * inv;
  r.y = (w0 * o0.y + w1 * o1.y) * inv;
  r.z = (w0 * o0.z + w1 * o1.z) * inv;
  r.w = (w0 * o0.w + w1 * o1.w) * inv;
  *(float4*)(out + (size_t)row * C_DIM + c) = r;
}

// ---------------------------------------------------------------------------
extern "C" void kernel_launch(void* const* d_in, const int* in_sizes, int n_in,
                              void* d_out, int out_size, void* d_ws, size_t ws_size,
                              hipStream_t stream) {
  const float* x    = (const float*)d_in[0];
  const float* W    = (const float*)d_in[1];
  const float* b    = (const float*)d_in[2];
  const int* n_padd = (const int*)d_in[3];
  float* out = (float*)d_out;

  const int T = in_sizes[0] / C_DIM;
  float* qkv   = (float*)d_ws;                          // T*3072 floats (48 MB)
  float* part1 = qkv + (size_t)T * N_DIM;               // T*1024 floats (16 MB)
  float2* ml   = (float2*)(part1 + (size_t)T * C_DIM);  // T*2 float2  (64 KB)

  dim3 g1(N_DIM / GT, (T + GT - 1) / GT);
  qkv_gemm<<<g1, 256, 0, stream>>>(x, W, b, qkv, T);

  const int ntiles = T / BQ;
  attn_flash2<<<2 * ntiles, 256, 0, stream>>>(qkv, n_padd, out, part1, ml, T);

  attn_merge<<<T, 256, 0, stream>>>(out, part1, ml, n_padd, T);
}

// Round 5
// 823.262 us; speedup vs baseline: 3.9037x; 2.0552x over previous
//
#include <hip/hip_runtime.h>
#include <hip/hip_bf16.h>
#include <math.h>

#define C_DIM 1024
#define N_DIM 3072   // 3*C

typedef __attribute__((ext_vector_type(8))) short bf16x8;   // 8 bf16 = 4 VGPRs
typedef __attribute__((ext_vector_type(4))) float f32x4;    // MFMA C/D

__device__ __forceinline__ unsigned short f2bf(float f) {
  __hip_bfloat16 h = __float2bfloat16(f);
  return *(reinterpret_cast<unsigned short*>(&h));
}
__device__ __forceinline__ float bf2f(unsigned short u) {
  return __uint_as_float(((unsigned int)u) << 16);
}
__device__ __forceinline__ f32x4 mfma16(bf16x8 a, bf16x8 b, f32x4 c) {
  return __builtin_amdgcn_mfma_f32_16x16x32_bf16(a, b, c, 0, 0, 0);
}

// ---------------------------------------------------------------------------
// Kernel 1: qkv = x @ W + b  (fp32 compute, proven) -> now writes BF16 qkv
// ---------------------------------------------------------------------------
#define GT 128
#define GK 16

__device__ __forceinline__ void fma44(float (&c)[4][4], const float4& a, const float4& b) {
  const float av[4] = {a.x, a.y, a.z, a.w};
  const float bv[4] = {b.x, b.y, b.z, b.w};
#pragma unroll
  for (int i = 0; i < 4; ++i)
#pragma unroll
    for (int j = 0; j < 4; ++j) c[i][j] += av[i] * bv[j];
}

__global__ __launch_bounds__(256) void qkv_gemm(
    const float* __restrict__ x, const float* __restrict__ W,
    const float* __restrict__ bias, unsigned short* __restrict__ qkvb, int T) {
  __shared__ float As[GK][GT];
  __shared__ float Bs[GK][GT];
  const int tid  = threadIdx.x;
  const int row0 = blockIdx.y * GT;
  const int col0 = blockIdx.x * GT;
  const int tm = (tid >> 4) << 2;
  const int tn = (tid & 15) << 2;
  const int ar = tid >> 1;
  const int ac = (tid & 1) << 3;
  const int br = tid >> 4;
  const int bc = (tid & 15) << 3;

  float acc[2][2][4][4] = {};

  const float* xp = x + (size_t)(row0 + ar) * C_DIM + ac;
  const float* wp = W + (size_t)br * N_DIM + col0 + bc;

  for (int k0 = 0; k0 < C_DIM; k0 += GK) {
    float4 a0 = *(const float4*)(xp + k0);
    float4 a1 = *(const float4*)(xp + k0 + 4);
    float4 b0 = *(const float4*)(wp + (size_t)k0 * N_DIM);
    float4 b1 = *(const float4*)(wp + (size_t)k0 * N_DIM + 4);
    __syncthreads();
    As[ac + 0][ar] = a0.x; As[ac + 1][ar] = a0.y;
    As[ac + 2][ar] = a0.z; As[ac + 3][ar] = a0.w;
    As[ac + 4][ar] = a1.x; As[ac + 5][ar] = a1.y;
    As[ac + 6][ar] = a1.z; As[ac + 7][ar] = a1.w;
    *(float4*)&Bs[br][bc]     = b0;
    *(float4*)&Bs[br][bc + 4] = b1;
    __syncthreads();
#pragma unroll
    for (int k = 0; k < GK; ++k) {
      float4 aL = *(const float4*)&As[k][tm];
      float4 aH = *(const float4*)&As[k][tm + 64];
      float4 bL = *(const float4*)&Bs[k][tn];
      float4 bH = *(const float4*)&Bs[k][tn + 64];
      fma44(acc[0][0], aL, bL);
      fma44(acc[0][1], aL, bH);
      fma44(acc[1][0], aH, bL);
      fma44(acc[1][1], aH, bH);
    }
  }

#pragma unroll
  for (int qi = 0; qi < 2; ++qi) {
#pragma unroll
    for (int i = 0; i < 4; ++i) {
      const int row = row0 + qi * 64 + tm + i;
#pragma unroll
      for (int qj = 0; qj < 2; ++qj) {
        const int col = col0 + qj * 64 + tn;
        ushort4 u;
        u.x = f2bf(acc[qi][qj][i][0] + bias[col + 0]);
        u.y = f2bf(acc[qi][qj][i][1] + bias[col + 1]);
        u.z = f2bf(acc[qi][qj][i][2] + bias[col + 2]);
        u.w = f2bf(acc[qi][qj][i][3] + bias[col + 3]);
        *(ushort4*)(qkvb + (size_t)row * N_DIM + col) = u;
      }
    }
  }
}

// ---------------------------------------------------------------------------
// Kernel 2: flash attention, bf16 MFMA (16x16x32), BQ=32, BK=128.
// Verified layouts: A[m=lane&15][k=quad*8+j]; B[k=quad*8+j][n=lane&15];
// C/D col=lane&15, row=quad*4+reg.  P round-trips LDS (C-layout -> A-layout).
// Up to 4 key-segments per tile; unnormalized O + (m,l) merged by kernel 3.
// ---------------------------------------------------------------------------
__global__ __launch_bounds__(256, 2) void attn_mfma(
    const unsigned short* __restrict__ qkvb, const int* __restrict__ np_p,
    float* __restrict__ out, float* __restrict__ part,
    float2* __restrict__ ml, int T, int nblocks) {
  __shared__ __align__(16) unsigned short Qs[32][72];    // [row][c]  4.6 KB
  __shared__ __align__(16) unsigned short Ks[128][72];   // [key][c] 18.4 KB
  __shared__ __align__(16) unsigned short Vt[64][136];   // [col][key] 17.4 KB
  __shared__ __align__(16) unsigned short Ps[32][136];   // [row][key] 8.7 KB
  __shared__ float mw[4][32];
  __shared__ float lw[4][32];

  const int tid  = threadIdx.x;
  const int lane = tid & 63;
  const int w    = tid >> 6;
  const int qd   = lane >> 4;    // quad
  const int n16  = lane & 15;

  // block -> (tile, seg); reversed so biggest blocks dispatch first
  int rb = (nblocks - 1) - (int)blockIdx.x;
  int g = 0;
  while (rb >= 32 * (g + 1)) { rb -= 32 * (g + 1); ++g; }
  const int tile = g * 32 + (rb & 31);
  const int seg  = rb >> 5;
  const int nseg = g + 1;
  const int row0 = tile * 32;
  const int kmax = row0 + 32;
  const int nch  = (kmax + 127) >> 7;
  const int cbase = nch / nseg, cext = nch % nseg;
  const int ch0 = seg * cbase + (seg < cext ? seg : cext);
  const int ch1 = ch0 + cbase + (seg < cext ? 1 : 0);
  const int np = *np_p;

  f32x4 o[16][2];                 // [col-slice][row-tile]
#pragma unroll
  for (int cs = 0; cs < 16; ++cs)
#pragma unroll
    for (int rt = 0; rt < 2; ++rt) o[cs][rt] = (f32x4){0.f, 0.f, 0.f, 0.f};
  float m_i[2][4], l_i[2][4];     // rows: rt*16 + qd*4 + r
#pragma unroll
  for (int rt = 0; rt < 2; ++rt)
#pragma unroll
    for (int r = 0; r < 4; ++r) { m_i[rt][r] = -3.0e38f; l_i[rt][r] = 0.f; }

  const int qr = tid >> 3, qc = (tid & 7) << 3;   // Q staging map
  const int kr = tid >> 3, kc = (tid & 7) << 3;   // K staging map (unit 0)

  for (int ch = ch0; ch < ch1; ++ch) {
    const int kc0 = ch << 7;
    f32x4 s[2][2];
#pragma unroll
    for (int rt = 0; rt < 2; ++rt)
#pragma unroll
      for (int kt = 0; kt < 2; ++kt) s[rt][kt] = (f32x4){0.f, 0.f, 0.f, 0.f};

    // ---- S = Q K^T over 16 k-slices of 64
    for (int ks = 0; ks < C_DIM; ks += 64) {
      uint4 qv = *(const uint4*)(qkvb + (size_t)(row0 + qr) * N_DIM + ks + qc);
      const unsigned short* kb_g = qkvb + C_DIM + ks + kc;
      uint4 kv0 = *(const uint4*)(kb_g + (size_t)(kc0 + kr)      * N_DIM);
      uint4 kv1 = *(const uint4*)(kb_g + (size_t)(kc0 + kr + 32) * N_DIM);
      uint4 kv2 = *(const uint4*)(kb_g + (size_t)(kc0 + kr + 64) * N_DIM);
      uint4 kv3 = *(const uint4*)(kb_g + (size_t)(kc0 + kr + 96) * N_DIM);
      __syncthreads();
      *(uint4*)&Qs[qr][qc] = qv;
      *(uint4*)&Ks[kr     ][kc] = kv0;
      *(uint4*)&Ks[kr + 32][kc] = kv1;
      *(uint4*)&Ks[kr + 64][kc] = kv2;
      *(uint4*)&Ks[kr + 96][kc] = kv3;
      __syncthreads();
#pragma unroll
      for (int kb = 0; kb < 2; ++kb) {
        const int c = (kb << 5) + (qd << 3);
        bf16x8 a0 = *(const bf16x8*)&Qs[n16][c];
        bf16x8 a1 = *(const bf16x8*)&Qs[16 + n16][c];
        bf16x8 b0 = *(const bf16x8*)&Ks[(w << 5) + n16][c];
        bf16x8 b1 = *(const bf16x8*)&Ks[(w << 5) + 16 + n16][c];
        s[0][0] = mfma16(a0, b0, s[0][0]);
        s[0][1] = mfma16(a0, b1, s[0][1]);
        s[1][0] = mfma16(a1, b0, s[1][0]);
        s[1][1] = mfma16(a1, b1, s[1][1]);
      }
    }

    // ---- online softmax (16-lane reduce + cross-wave LDS combine)
    float al[2][4];
#pragma unroll
    for (int rt = 0; rt < 2; ++rt) {
#pragma unroll
      for (int r = 0; r < 4; ++r) {
        const int rowg = row0 + (rt << 4) + (qd << 2) + r;
        const int j0 = kc0 + (w << 5) + n16;
        const int j1 = j0 + 16;
        float sv0 = ((j0 <= rowg) && (j0 >= np)) ? s[rt][0][r] * 0.03125f : -3.0e38f;
        float sv1 = ((j1 <= rowg) && (j1 >= np)) ? s[rt][1][r] * 0.03125f : -3.0e38f;
        s[rt][0][r] = sv0; s[rt][1][r] = sv1;
        float m2 = fmaxf(sv0, sv1);
        m2 = fmaxf(m2, __shfl_xor(m2, 1));
        m2 = fmaxf(m2, __shfl_xor(m2, 2));
        m2 = fmaxf(m2, __shfl_xor(m2, 4));
        m2 = fmaxf(m2, __shfl_xor(m2, 8));
        if (n16 == r) mw[w][(rt << 4) + (qd << 2) + r] = m2;
      }
    }
    __syncthreads();
#pragma unroll
    for (int rt = 0; rt < 2; ++rt) {
#pragma unroll
      for (int r = 0; r < 4; ++r) {
        const int row = (rt << 4) + (qd << 2) + r;
        float mn = fmaxf(fmaxf(mw[0][row], mw[1][row]), fmaxf(mw[2][row], mw[3][row]));
        mn = fmaxf(mn, m_i[rt][r]);
        al[rt][r] = __expf(m_i[rt][r] - mn);
        m_i[rt][r] = mn;
        float p0 = (s[rt][0][r] > -1.0e30f) ? __expf(s[rt][0][r] - mn) : 0.f;
        float p1 = (s[rt][1][r] > -1.0e30f) ? __expf(s[rt][1][r] - mn) : 0.f;
        Ps[row][(w << 5) + n16]      = f2bf(p0);
        Ps[row][(w << 5) + 16 + n16] = f2bf(p1);
        float ls = p0 + p1;
        ls += __shfl_xor(ls, 1);
        ls += __shfl_xor(ls, 2);
        ls += __shfl_xor(ls, 4);
        ls += __shfl_xor(ls, 8);
        if (n16 == r) lw[w][row] = ls;
      }
    }
    __syncthreads();
#pragma unroll
    for (int rt = 0; rt < 2; ++rt)
#pragma unroll
      for (int r = 0; r < 4; ++r) {
        const int row = (rt << 4) + (qd << 2) + r;
        l_i[rt][r] = l_i[rt][r] * al[rt][r] +
                     (lw[0][row] + lw[1][row] + lw[2][row] + lw[3][row]);
      }
#pragma unroll
    for (int cs = 0; cs < 16; ++cs)
#pragma unroll
      for (int rt = 0; rt < 2; ++rt) {
        o[cs][rt][0] *= al[rt][0];
        o[cs][rt][1] *= al[rt][1];
        o[cs][rt][2] *= al[rt][2];
        o[cs][rt][3] *= al[rt][3];
      }

    // ---- O += P V over 16 col-slices of 64 (V transposed into LDS)
#pragma unroll 1
    for (int cs = 0; cs < 16; ++cs) {
      const int csb = cs << 6;
      const int kp0 = tid >> 3, cg0 = tid & 7;
      const size_t vr0 = (size_t)(kc0 + (kp0 << 1)) * N_DIM + 2 * C_DIM + csb + (cg0 << 3);
      uint4 va0 = *(const uint4*)(qkvb + vr0);
      uint4 va1 = *(const uint4*)(qkvb + vr0 + N_DIM);
      const size_t vr1 = vr0 + (size_t)64 * N_DIM;
      uint4 vb0 = *(const uint4*)(qkvb + vr1);
      uint4 vb1 = *(const uint4*)(qkvb + vr1 + N_DIM);
      __syncthreads();
#define PK(lo, hi) ((unsigned int)(lo) | ((unsigned int)(hi) << 16))
      {
        const int cb = cg0 << 3, kk2 = kp0 << 1;
        *(unsigned int*)&Vt[cb + 0][kk2] = PK(va0.x & 0xffff, va1.x & 0xffff);
        *(unsigned int*)&Vt[cb + 1][kk2] = PK(va0.x >> 16,    va1.x >> 16);
        *(unsigned int*)&Vt[cb + 2][kk2] = PK(va0.y & 0xffff, va1.y & 0xffff);
        *(unsigned int*)&Vt[cb + 3][kk2] = PK(va0.y >> 16,    va1.y >> 16);
        *(unsigned int*)&Vt[cb + 4][kk2] = PK(va0.z & 0xffff, va1.z & 0xffff);
        *(unsigned int*)&Vt[cb + 5][kk2] = PK(va0.z >> 16,    va1.z >> 16);
        *(unsigned int*)&Vt[cb + 6][kk2] = PK(va0.w & 0xffff, va1.w & 0xffff);
        *(unsigned int*)&Vt[cb + 7][kk2] = PK(va0.w >> 16,    va1.w >> 16);
        const int kk2b = kk2 + 64;
        *(unsigned int*)&Vt[cb + 0][kk2b] = PK(vb0.x & 0xffff, vb1.x & 0xffff);
        *(unsigned int*)&Vt[cb + 1][kk2b] = PK(vb0.x >> 16,    vb1.x >> 16);
        *(unsigned int*)&Vt[cb + 2][kk2b] = PK(vb0.y & 0xffff, vb1.y & 0xffff);
        *(unsigned int*)&Vt[cb + 3][kk2b] = PK(vb0.y >> 16,    vb1.y >> 16);
        *(unsigned int*)&Vt[cb + 4][kk2b] = PK(vb0.z & 0xffff, vb1.z & 0xffff);
        *(unsigned int*)&Vt[cb + 5][kk2b] = PK(vb0.z >> 16,    vb1.z >> 16);
        *(unsigned int*)&Vt[cb + 6][kk2b] = PK(vb0.w & 0xffff, vb1.w & 0xffff);
        *(unsigned int*)&Vt[cb + 7][kk2b] = PK(vb0.w >> 16,    vb1.w >> 16);
      }
#undef PK
      __syncthreads();
#pragma unroll
      for (int kb = 0; kb < 4; ++kb) {
        const int kk = (kb << 5) + (qd << 3);
        bf16x8 pa0 = *(const bf16x8*)&Ps[n16][kk];
        bf16x8 pa1 = *(const bf16x8*)&Ps[16 + n16][kk];
        bf16x8 vb  = *(const bf16x8*)&Vt[(w << 4) + n16][kk];
        o[cs][0] = mfma16(pa0, vb, o[cs][0]);
        o[cs][1] = mfma16(pa1, vb, o[cs][1]);
      }
    }
  }

  // ---- epilogue: unnormalized O + (m,l)
  float* dst;
  int radj;
  if (seg == 0) { dst = out; radj = 0; }
  else {
    dst = part + ((size_t)(seg - 1) * T - (size_t)(seg * (seg - 1) / 2) * 1024) * C_DIM;
    radj = seg << 10;
  }
#pragma unroll
  for (int cs = 0; cs < 16; ++cs)
#pragma unroll
    for (int rt = 0; rt < 2; ++rt)
#pragma unroll
      for (int r = 0; r < 4; ++r) {
        const int row = row0 + (rt << 4) + (qd << 2) + r;
        const int col = (cs << 6) + (w << 4) + n16;
        dst[(size_t)(row - radj) * C_DIM + col] = o[cs][rt][r];
      }
  if (w == 0 && n16 == 0) {
#pragma unroll
    for (int rt = 0; rt < 2; ++rt)
#pragma unroll
      for (int r = 0; r < 4; ++r) {
        const int row = row0 + (rt << 4) + (qd << 2) + r;
        ml[(size_t)seg * T + row] = make_float2(m_i[rt][r], l_i[rt][r]);
      }
  }

  // ---- padded rows (< n_padd): uniform over ALL T keys, final values (seg0)
  if (seg == 0 && np > row0) {
    const int pc = min(np - row0, 32);
    const int c4 = tid << 2;
    float a0 = 0.f, a1 = 0.f, a2 = 0.f, a3 = 0.f;
    for (int j = 0; j < T; ++j) {
      ushort4 v = *(const ushort4*)(qkvb + (size_t)j * N_DIM + 2 * C_DIM + c4);
      a0 += bf2f(v.x); a1 += bf2f(v.y); a2 += bf2f(v.z); a3 += bf2f(v.w);
    }
    const float inv = 1.0f / (float)T;
    float4 rv = {a0 * inv, a1 * inv, a2 * inv, a3 * inv};
    for (int r = 0; r < pc; ++r)
      *(float4*)(out + (size_t)(row0 + r) * C_DIM + c4) = rv;
  }
}

// ---------------------------------------------------------------------------
// Kernel 3: merge up to 4 segments per row
// ---------------------------------------------------------------------------
__global__ __launch_bounds__(256) void attn_merge4(
    float* __restrict__ out, const float* __restrict__ part,
    const float2* __restrict__ ml, const int* __restrict__ np_p, int T) {
  const int row = blockIdx.x;
  if (row < *np_p) return;
  const int ns = (row >> 10) + 1;
  const int c = threadIdx.x << 2;
  float2 m0 = ml[row];
  if (ns == 1) {
    const float inv = 1.0f / m0.y;
    float4 o0 = *(const float4*)(out + (size_t)row * C_DIM + c);
    o0.x *= inv; o0.y *= inv; o0.z *= inv; o0.w *= inv;
    *(float4*)(out + (size_t)row * C_DIM + c) = o0;
    return;
  }
  float2 ms[3];
  float M = m0.x;
  for (int s = 1; s < ns; ++s) { ms[s-1] = ml[(size_t)s * T + row]; M = fmaxf(M, ms[s-1].x); }
  const float w0 = __expf(m0.x - M);
  float L = w0 * m0.y;
  float ws[3];
  for (int s = 1; s < ns; ++s) { ws[s-1] = __expf(ms[s-1].x - M); L += ws[s-1] * ms[s-1].y; }
  const float inv = 1.0f / L;
  float4 acc = *(const float4*)(out + (size_t)row * C_DIM + c);
  acc.x *= w0; acc.y *= w0; acc.z *= w0; acc.w *= w0;
  for (int s = 1; s < ns; ++s) {
    const float* pp = part + ((size_t)(s - 1) * T - (size_t)(s * (s - 1) / 2) * 1024) * C_DIM
                    + (size_t)(row - (s << 10)) * C_DIM + c;
    float4 p = *(const float4*)pp;
    acc.x += ws[s-1] * p.x; acc.y += ws[s-1] * p.y;
    acc.z += ws[s-1] * p.z; acc.w += ws[s-1] * p.w;
  }
  acc.x *= inv; acc.y *= inv; acc.z *= inv; acc.w *= inv;
  *(float4*)(out + (size_t)row * C_DIM + c) = acc;
}

// ---------------------------------------------------------------------------
extern "C" void kernel_launch(void* const* d_in, const int* in_sizes, int n_in,
                              void* d_out, int out_size, void* d_ws, size_t ws_size,
                              hipStream_t stream) {
  const float* x    = (const float*)d_in[0];
  const float* W    = (const float*)d_in[1];
  const float* b    = (const float*)d_in[2];
  const int* n_padd = (const int*)d_in[3];
  float* out = (float*)d_out;

  const int T = in_sizes[0] / C_DIM;
  unsigned short* qkvb = (unsigned short*)d_ws;              // T*3072 bf16 = 24 MB
  float* part = (float*)(qkvb + (size_t)T * N_DIM);          // (3T-6144) rows fp32 = 24 MB
  float2* ml  = (float2*)(part + (size_t)(3 * T - 6144) * C_DIM);  // 4*T float2

  dim3 g1(N_DIM / GT, (T + GT - 1) / GT);
  qkv_gemm<<<g1, 256, 0, stream>>>(x, W, b, qkvb, T);

  const int ntiles = T / 32;
  int nblk = 0;
  for (int t = 0; t < ntiles; ++t) nblk += t / 32 + 1;
  attn_mfma<<<nblk, 256, 0, stream>>>(qkvb, n_padd, out, part, ml, T, nblk);

  attn_merge4<<<T, 256, 0, stream>>>(out, part, ml, n_padd, T);
}